// Round 1
// baseline (229.816 us; speedup 1.0000x reference)
//
#include <hip/hip_runtime.h>
#include <hip/hip_bf16.h>
#include <hip/hip_fp16.h>

// DisenHAN fused, single-pass FP16 MFMA edition, v16 (gfx950).
// v16 = v15 with TWO batches per block (grid (B/2, 2)) + fp16 sC.
// Theory: v15 is latency-bound (VALU 47%, HBM 23%, Mfma 6%, Occ 34%) with
// residency capped at 4 blocks/CU by LDS (35.8KB) and a grid sized to
// exactly one round. This round's single variable: residency.
//  - 2 batches/block -> 2048 blocks, 8 slots/wave, sC = 32 rows.
//  - sC stored fp16 (pitch 72 halfs, 16B-aligned rows): h1 was already
//    cast to fp16 for the layer-0 MFMA, so only the routing center c4
//    (hid) sees new rounding (~2.4e-4). Layer-0 A-frags now load as
//    half8 directly (16 cvts removed from the tail).
//  - LDS: sN 17408 + sC 4608 + sE0 512 = 22528B -> 7 blocks/CU (28 waves,
//    was 16). __launch_bounds__(256,7) caps VGPR at 73 (current use 60).
// v15 recap: 4-block pack kernel -> fp16 B-frags in d_ws; single-pass
// mfma_f32_16x16x32_f16; no-max softmax (logits ~N(0,1)); software-
// pipelined slot loop w/ double-buffered acc; register-resident routing
// (rr=lane>>4 rows, j4=lane&15 cols; Nv once per slot; softmax+z via
// shfl_xor; htmp in regs); h1 overwrites its dead hid row in sC.
// T=1 collapses hete-attention: beta==1, wp==1 forever.

#define NTH 256

typedef __attribute__((ext_vector_type(8))) _Float16 half8;  // 8 fp16 (4 VGPRs)
typedef __attribute__((ext_vector_type(4))) _Float16 half4;
typedef __attribute__((ext_vector_type(4))) float floatx4;

__device__ __forceinline__ half8 pack8_f16(float4 a, float4 b) {
    half8 r;
    r[0] = (_Float16)a.x; r[1] = (_Float16)a.y;
    r[2] = (_Float16)a.z; r[3] = (_Float16)a.w;
    r[4] = (_Float16)b.x; r[5] = (_Float16)b.y;
    r[6] = (_Float16)b.z; r[7] = (_Float16)b.w;
    return r;
}

// ---- setup: pack 4 weight matrices into fp16 B-fragment order ----
// layout: frag[ (w*4+nt)*2+ks ][ lane ] = 8 fp16 (16B), coalesced.
__global__ void pack_weights(const float* __restrict__ W0u, const float* __restrict__ W0i,
                             const float* __restrict__ W1u, const float* __restrict__ W1i,
                             half8* __restrict__ pk) {
    const float* Ws[4] = {W0u, W0i, W1u, W1i};
    const int w = blockIdx.x;
    const int wv = threadIdx.x >> 6, lane = threadIdx.x & 63;
    const int quad = lane >> 4, m16 = lane & 15;
    const int nt = wv;
    const float* W = Ws[w];
#pragma unroll
    for (int ks = 0; ks < 2; ++ks) {
        half8 f;
#pragma unroll
        for (int j = 0; j < 8; ++j)
            f[j] = (_Float16)W[(ks * 32 + quad * 8 + j) * 64 + nt * 16 + m16];
        pk[(long)(((w * 4 + nt) * 2 + ks)) * 64 + lane] = f;
    }
}

__global__ __launch_bounds__(256, 7)
void disenhan_mfma(const float* __restrict__ user_table,
                   const float* __restrict__ item_table,
                   const half8* __restrict__ pk,
                   const int* __restrict__ uidx0, const int* __restrict__ uidx1,
                   const int* __restrict__ uidx2,
                   const int* __restrict__ iidx0, const int* __restrict__ iidx1,
                   const int* __restrict__ iidx2,
                   float* __restrict__ out, int B)
{
    constexpr float SCALE = 0.35355339059327373f;  // 1/sqrt(8)
    constexpr int SCP = 72;   // sC pitch in halfs (144B: 16B-aligned rows)
    const int branch = blockIdx.y;
    const int tid = threadIdx.x;
    const int wv = tid >> 6, lane = tid & 63;
    const int quad = lane >> 4;   // MFMA k-block selector
    const int m16  = lane & 15;   // MFMA row (A) / col (B,D) selector
    const int rr   = lane >> 4;   // routing: row group (rows 4rr..4rr+3)
    const int j4   = lane & 15;   // routing: col group (cols 4j4..4j4+3)

    const int b_base = blockIdx.x * 2;
    int bidx[2];
#pragma unroll
    for (int bb = 0; bb < 2; ++bb) {
        int bc = b_base + bb;
        bidx[bb] = (bc < B) ? bc : (B - 1);   // tail guard: duplicate work, benign
    }

    // matrix ids in pk: 0=W0u 1=W0i 2=W1u 3=W1i
    const float *tab0, *tab1;
    const int *idx0, *idx1, *idx2;
    int w1c_id, w1n_id, w0n_id;
    if (branch == 0) { tab0 = user_table; tab1 = item_table;
                       idx0 = uidx0; idx1 = uidx1; idx2 = uidx2;
                       w1c_id = 3; w1n_id = 2; w0n_id = 1; }
    else             { tab0 = item_table; tab1 = user_table;
                       idx0 = iidx0; idx1 = iidx1; idx2 = iidx2;
                       w1c_id = 2; w1n_id = 3; w0n_id = 0; }

    __shared__ float    sN[4][16 * 68];  // per-wave nh tile (fp32, pitch 68)
    __shared__ _Float16 sC[32 * SCP];    // hid rows (2 batches x 16, fp16); h1 overwrites
    __shared__ float    sE0[2][64];      // layer-0 centers (e0), one per batch

    // e0 prefetch: wave wv (wv<2) serves batch bidx[wv] in the tail
    float v0 = 0.f;
    if (wv < 2) v0 = tab0[(long)idx0[bidx[wv]] * 64 + lane];

    // ---- B-fragment loader: 8 coalesced 16B loads from the packed buffer ----
    half8 wf[4][2];
    auto load_wfrag = [&](int w) {
#pragma unroll
        for (int nt = 0; nt < 4; ++nt)
#pragma unroll
            for (int ks = 0; ks < 2; ++ks)
                wf[nt][ks] = pk[(long)(((w * 4 + nt) * 2 + ks)) * 64 + lane];
    };

    // ---- MFMA tile compute (no LDS side effects) ----
    auto mfma_compute_h = [&](half8 A0, half8 A1, floatx4* acc) {
#pragma unroll
        for (int nt = 0; nt < 4; ++nt) {
            acc[nt] = (floatx4){0.f, 0.f, 0.f, 0.f};
            acc[nt] = __builtin_amdgcn_mfma_f32_16x16x32_f16(A0, wf[nt][0], acc[nt], 0, 0, 0);
            acc[nt] = __builtin_amdgcn_mfma_f32_16x16x32_f16(A1, wf[nt][1], acc[nt], 0, 0, 0);
        }
    };
    auto mfma_compute = [&](float4 f0, float4 f1, float4 f2, float4 f3,
                            floatx4* acc) {
        mfma_compute_h(pack8_f16(f0, f1), pack8_f16(f2, f3), acc);
    };
    auto store_tile = [&](const floatx4* acc, float* __restrict__ Nw) {
#pragma unroll
        for (int nt = 0; nt < 4; ++nt)
#pragma unroll
            for (int rg = 0; rg < 4; ++rg)
                Nw[(quad * 4 + rg) * 68 + nt * 16 + m16] = acc[nt][rg];
    };

    // ---- register-resident routing: 3 iterations, no-max softmax (v13) ----
    auto routing_reg = [&](const float4* Nv, float4 c4, bool relu_last) -> float4 {
        float4 h4 = c4;   // iter-0 htmp = hid
#pragma unroll
        for (int it = 0; it < 3; ++it) {
            float es[4];
#pragma unroll
            for (int t = 0; t < 4; ++t) {
                float d = h4.x * Nv[t].x + h4.y * Nv[t].y +
                          h4.z * Nv[t].z + h4.w * Nv[t].w;
                d += __shfl_xor(d, 1);        // + other half of the octet
                es[t] = __expf(d * SCALE);
            }
            float sm = (es[0] + es[1]) + (es[2] + es[3]);
            sm += __shfl_xor(sm, 16);
            sm += __shfl_xor(sm, 32);
            float inv = 1.0f / sm;
            float a0 = es[0] * inv, a1 = es[1] * inv;
            float a2 = es[2] * inv, a3 = es[3] * inv;
            float4 z;
            z.x = a0 * Nv[0].x; z.y = a0 * Nv[0].y; z.z = a0 * Nv[0].z; z.w = a0 * Nv[0].w;
            z.x = fmaf(a1, Nv[1].x, z.x); z.y = fmaf(a1, Nv[1].y, z.y);
            z.z = fmaf(a1, Nv[1].z, z.z); z.w = fmaf(a1, Nv[1].w, z.w);
            z.x = fmaf(a2, Nv[2].x, z.x); z.y = fmaf(a2, Nv[2].y, z.y);
            z.z = fmaf(a2, Nv[2].z, z.z); z.w = fmaf(a2, Nv[2].w, z.w);
            z.x = fmaf(a3, Nv[3].x, z.x); z.y = fmaf(a3, Nv[3].y, z.y);
            z.z = fmaf(a3, Nv[3].z, z.z); z.w = fmaf(a3, Nv[3].w, z.w);
            z.x += __shfl_xor(z.x, 16); z.y += __shfl_xor(z.y, 16);
            z.z += __shfl_xor(z.z, 16); z.w += __shfl_xor(z.w, 16);
            z.x += __shfl_xor(z.x, 32); z.y += __shfl_xor(z.y, 32);
            z.z += __shfl_xor(z.z, 32); z.w += __shfl_xor(z.w, 32);
            h4.x = c4.x + z.x; h4.y = c4.y + z.y;
            h4.z = c4.z + z.z; h4.w = c4.w + z.w;
            if (relu_last && it == 2) {
                h4.x = fmaxf(h4.x, 0.f); h4.y = fmaxf(h4.y, 0.f);
                h4.z = fmaxf(h4.z, 0.f); h4.w = fmaxf(h4.w, 0.f);
            }
        }
        return h4;
    };

    // rolling gidx loader: slot u -> batch u>>2, q = u&3   (u in 0..7)
    auto gload = [&](int u) {
        return idx2[bidx[u >> 2] * 256 + (wv * 4 + (u & 3)) * 16 + m16];
    };

    // ================= layer-1 pre-encode: hid = e1 @ W1c (2 batches) =========
    load_wfrag(w1c_id);
#pragma unroll
    for (int bb = 0; bb < 2; ++bb) {
        const float* p1 = &tab1[(long)idx1[bidx[bb] * 16 + m16] * 64 + quad * 8];
        float4 e1a = *(const float4*)p1;
        float4 e1b = *(const float4*)(p1 + 4);
        float4 e1c = *(const float4*)(p1 + 32);
        float4 e1d = *(const float4*)(p1 + 36);
        floatx4 hacc[4];
        mfma_compute(e1a, e1b, e1c, e1d, hacc);
        // D: row = quad*4+reg, col = nt*16+m16. Wave w keeps rows w*4..w*4+3
        // (quad==wv lanes) — exactly its own routing slots. fp16 store.
        if (quad == wv) {
#pragma unroll
            for (int nt = 0; nt < 4; ++nt)
#pragma unroll
                for (int rg = 0; rg < 4; ++rg)
                    sC[(bb * 16 + quad * 4 + rg) * SCP + nt * 16 + m16] =
                        (_Float16)hacc[nt][rg];
        }
    }
    __builtin_amdgcn_wave_barrier();

    // ================= layer-1 main: 8 slots (2 batches x 4), pipelined ======
    load_wfrag(w1n_id);
    float4 f0, f1, f2, f3;
    {
        const float* p = &tab0[(long)gload(0) * 64 + quad * 8];
        f0 = *(const float4*)p;        f1 = *(const float4*)(p + 4);
        f2 = *(const float4*)(p + 32); f3 = *(const float4*)(p + 36);
    }
    floatx4 accA[4], accB[4];
    mfma_compute(f0, f1, f2, f3, accA);           // slot 0
    {
        const float* p = &tab0[(long)gload(1) * 64 + quad * 8];
        f0 = *(const float4*)p;        f1 = *(const float4*)(p + 4);
        f2 = *(const float4*)(p + 32); f3 = *(const float4*)(p + 36);
    }
#pragma unroll
    for (int u = 0; u < 8; ++u) {
        const int srow = (u >> 2) * 16 + wv * 4 + (u & 3);
        const floatx4* accCur = (u & 1) ? accB : accA;
        floatx4* accNxt       = (u & 1) ? accA : accB;
        __builtin_amdgcn_wave_barrier();
        store_tile(accCur, sN[wv]);
        __builtin_amdgcn_wave_barrier();
        float4 Nv[4];
#pragma unroll
        for (int t = 0; t < 4; ++t)
            Nv[t] = *(const float4*)&sN[wv][(4 * rr + t) * 68 + 4 * j4];
        __builtin_amdgcn_wave_barrier();
        if (u < 7) {
            mfma_compute(f0, f1, f2, f3, accNxt);  // slot u+1, overlaps routing(u)
            if (u < 6) {   // prefetch slot u+2's A rows (rolling gidx)
                const float* p = &tab0[(long)gload(u + 2) * 64 + quad * 8];
                f0 = *(const float4*)p;        f1 = *(const float4*)(p + 4);
                f2 = *(const float4*)(p + 32); f3 = *(const float4*)(p + 36);
            }
        }
        half4 ch = *(const half4*)&sC[srow * SCP + 4 * j4];  // reg-held hid (fp16)
        float4 c4;
        c4.x = (float)ch[0]; c4.y = (float)ch[1];
        c4.z = (float)ch[2]; c4.w = (float)ch[3];
        float4 h4 = routing_reg(Nv, c4, true);
        if (rr == 0) {   // h1 overwrites dead hid row (fp16)
            half4 hh;
            hh[0] = (_Float16)h4.x; hh[1] = (_Float16)h4.y;
            hh[2] = (_Float16)h4.z; hh[3] = (_Float16)h4.w;
            *(half4*)&sC[srow * SCP + 4 * j4] = hh;
        }
    }

    // ================= layer-0: wave wv (wv<2) -> batch bidx[wv] ==============
    __syncthreads();   // the only block barrier: all h1 rows visible
    if (wv < 2) {
        load_wfrag(w0n_id);
        sE0[wv][lane] = v0;
        floatx4 acc[4];
        {
            // batch wv's h1 rows, already fp16: load A-frags directly
            const _Float16* hp = &sC[(wv * 16 + m16) * SCP];
            half8 A0 = *(const half8*)(hp + quad * 8);
            half8 A1 = *(const half8*)(hp + 32 + quad * 8);
            mfma_compute_h(A0, A1, acc);
        }
        __builtin_amdgcn_wave_barrier();
        store_tile(acc, sN[wv]);
        __builtin_amdgcn_wave_barrier();
        float4 Nv[4];
#pragma unroll
        for (int t = 0; t < 4; ++t)
            Nv[t] = *(const float4*)&sN[wv][(4 * rr + t) * 68 + 4 * j4];
        float4 c4 = *(const float4*)&sE0[wv][4 * j4];
        float4 h4 = routing_reg(Nv, c4, false);   // no relu in layer-0
        if (rr == 0 && b_base + wv < B)
            *(float4*)&out[((long)branch * B + bidx[wv]) * 64 + 4 * j4] = h4;
    }
}

extern "C" void kernel_launch(void* const* d_in, const int* in_sizes, int n_in,
                              void* d_out, int out_size, void* d_ws, size_t ws_size,
                              hipStream_t stream) {
    const float* user_table = (const float*)d_in[0];
    const float* item_table = (const float*)d_in[1];
    const float* W0u = (const float*)d_in[2];
    const float* W0i = (const float*)d_in[3];
    const float* W1u = (const float*)d_in[4];
    const float* W1i = (const float*)d_in[5];
    const int* uidx0 = (const int*)d_in[6];
    const int* uidx1 = (const int*)d_in[7];
    const int* uidx2 = (const int*)d_in[8];
    const int* iidx0 = (const int*)d_in[9];
    const int* iidx1 = (const int*)d_in[10];
    const int* iidx2 = (const int*)d_in[11];
    float* out = (float*)d_out;
    half8* pk = (half8*)d_ws;   // 4 matrices * 8 frags * 64 lanes * 16B = 32 KB

    const int B = in_sizes[6];  // 2048
    hipLaunchKernelGGL(pack_weights, dim3(4), dim3(256), 0, stream,
                       W0u, W0i, W1u, W1i, pk);
    dim3 grid((B + 1) / 2, 2), block(NTH);
    hipLaunchKernelGGL(disenhan_mfma, grid, block, 0, stream,
                       user_table, item_table, (const half8*)pk,
                       uidx0, uidx1, uidx2, iidx0, iidx1, iidx2, out, B);
}

// Round 2
// 158.513 us; speedup vs baseline: 1.4498x; 1.4498x over previous
//
#include <hip/hip_runtime.h>
#include <hip/hip_bf16.h>
#include <hip/hip_fp16.h>

// DisenHAN fused, single-pass FP16 MFMA edition, v17 (gfx950).
// v17 = v16 with launch_bounds reverted (256,7)->(256,4).
// v16 post-mortem: forcing 7 waves/EU capped VGPR at ~73 and the compiler
// SPILLED (VGPR 60->36, WRITE_SIZE 1MB->91MB = scratch stores, FETCH
// +145MB = spill reloads). Occupancy rose 34->59% but VALUBusy fell
// 47->26% (waves stalled on scratch): 73->137us. Rule confirmed: the
// routing body needs ~60 live VGPRs; never bound tighter than (256,4).
// The residency levers are kept (untested by v16's spill disaster):
//  - 2 batches/block -> 2048 blocks, 8 slots/wave, sC = 32 rows.
//  - sC stored fp16 (pitch 72 halfs, 16B-aligned rows): h1 was already
//    fp16 for the layer-0 MFMA; only routing center c4 sees ~2.4e-4
//    rounding. Layer-0 A-frags load as half8 directly.
//  - LDS: sN 17408 + sC 4608 + sE0 512 = 22528B -> 7 blocks/CU by LDS;
//    with natural ~60 VGPRs (8 waves/EU capable) residency = 7 blocks/CU
//    (28 waves/CU) WITHOUT any launch-bounds forcing.
// v15 recap: 4-block pack kernel -> fp16 B-frags in d_ws; single-pass
// mfma_f32_16x16x32_f16; no-max softmax (logits ~N(0,1)); software-
// pipelined slot loop w/ double-buffered acc; register-resident routing
// (rr=lane>>4 rows, j4=lane&15 cols; Nv once per slot; softmax+z via
// shfl_xor; htmp in regs); h1 overwrites its dead hid row in sC.
// T=1 collapses hete-attention: beta==1, wp==1 forever.

#define NTH 256

typedef __attribute__((ext_vector_type(8))) _Float16 half8;  // 8 fp16 (4 VGPRs)
typedef __attribute__((ext_vector_type(4))) _Float16 half4;
typedef __attribute__((ext_vector_type(4))) float floatx4;

__device__ __forceinline__ half8 pack8_f16(float4 a, float4 b) {
    half8 r;
    r[0] = (_Float16)a.x; r[1] = (_Float16)a.y;
    r[2] = (_Float16)a.z; r[3] = (_Float16)a.w;
    r[4] = (_Float16)b.x; r[5] = (_Float16)b.y;
    r[6] = (_Float16)b.z; r[7] = (_Float16)b.w;
    return r;
}

// ---- setup: pack 4 weight matrices into fp16 B-fragment order ----
// layout: frag[ (w*4+nt)*2+ks ][ lane ] = 8 fp16 (16B), coalesced.
__global__ void pack_weights(const float* __restrict__ W0u, const float* __restrict__ W0i,
                             const float* __restrict__ W1u, const float* __restrict__ W1i,
                             half8* __restrict__ pk) {
    const float* Ws[4] = {W0u, W0i, W1u, W1i};
    const int w = blockIdx.x;
    const int wv = threadIdx.x >> 6, lane = threadIdx.x & 63;
    const int quad = lane >> 4, m16 = lane & 15;
    const int nt = wv;
    const float* W = Ws[w];
#pragma unroll
    for (int ks = 0; ks < 2; ++ks) {
        half8 f;
#pragma unroll
        for (int j = 0; j < 8; ++j)
            f[j] = (_Float16)W[(ks * 32 + quad * 8 + j) * 64 + nt * 16 + m16];
        pk[(long)(((w * 4 + nt) * 2 + ks)) * 64 + lane] = f;
    }
}

__global__ __launch_bounds__(256, 4)
void disenhan_mfma(const float* __restrict__ user_table,
                   const float* __restrict__ item_table,
                   const half8* __restrict__ pk,
                   const int* __restrict__ uidx0, const int* __restrict__ uidx1,
                   const int* __restrict__ uidx2,
                   const int* __restrict__ iidx0, const int* __restrict__ iidx1,
                   const int* __restrict__ iidx2,
                   float* __restrict__ out, int B)
{
    constexpr float SCALE = 0.35355339059327373f;  // 1/sqrt(8)
    constexpr int SCP = 72;   // sC pitch in halfs (144B: 16B-aligned rows)
    const int branch = blockIdx.y;
    const int tid = threadIdx.x;
    const int wv = tid >> 6, lane = tid & 63;
    const int quad = lane >> 4;   // MFMA k-block selector
    const int m16  = lane & 15;   // MFMA row (A) / col (B,D) selector
    const int rr   = lane >> 4;   // routing: row group (rows 4rr..4rr+3)
    const int j4   = lane & 15;   // routing: col group (cols 4j4..4j4+3)

    const int b_base = blockIdx.x * 2;
    int bidx[2];
#pragma unroll
    for (int bb = 0; bb < 2; ++bb) {
        int bc = b_base + bb;
        bidx[bb] = (bc < B) ? bc : (B - 1);   // tail guard: duplicate work, benign
    }

    // matrix ids in pk: 0=W0u 1=W0i 2=W1u 3=W1i
    const float *tab0, *tab1;
    const int *idx0, *idx1, *idx2;
    int w1c_id, w1n_id, w0n_id;
    if (branch == 0) { tab0 = user_table; tab1 = item_table;
                       idx0 = uidx0; idx1 = uidx1; idx2 = uidx2;
                       w1c_id = 3; w1n_id = 2; w0n_id = 1; }
    else             { tab0 = item_table; tab1 = user_table;
                       idx0 = iidx0; idx1 = iidx1; idx2 = iidx2;
                       w1c_id = 2; w1n_id = 3; w0n_id = 0; }

    __shared__ float    sN[4][16 * 68];  // per-wave nh tile (fp32, pitch 68)
    __shared__ _Float16 sC[32 * SCP];    // hid rows (2 batches x 16, fp16); h1 overwrites
    __shared__ float    sE0[2][64];      // layer-0 centers (e0), one per batch

    // e0 prefetch: wave wv (wv<2) serves batch bidx[wv] in the tail
    float v0 = 0.f;
    if (wv < 2) v0 = tab0[(long)idx0[bidx[wv]] * 64 + lane];

    // ---- B-fragment loader: 8 coalesced 16B loads from the packed buffer ----
    half8 wf[4][2];
    auto load_wfrag = [&](int w) {
#pragma unroll
        for (int nt = 0; nt < 4; ++nt)
#pragma unroll
            for (int ks = 0; ks < 2; ++ks)
                wf[nt][ks] = pk[(long)(((w * 4 + nt) * 2 + ks)) * 64 + lane];
    };

    // ---- MFMA tile compute (no LDS side effects) ----
    auto mfma_compute_h = [&](half8 A0, half8 A1, floatx4* acc) {
#pragma unroll
        for (int nt = 0; nt < 4; ++nt) {
            acc[nt] = (floatx4){0.f, 0.f, 0.f, 0.f};
            acc[nt] = __builtin_amdgcn_mfma_f32_16x16x32_f16(A0, wf[nt][0], acc[nt], 0, 0, 0);
            acc[nt] = __builtin_amdgcn_mfma_f32_16x16x32_f16(A1, wf[nt][1], acc[nt], 0, 0, 0);
        }
    };
    auto mfma_compute = [&](float4 f0, float4 f1, float4 f2, float4 f3,
                            floatx4* acc) {
        mfma_compute_h(pack8_f16(f0, f1), pack8_f16(f2, f3), acc);
    };
    auto store_tile = [&](const floatx4* acc, float* __restrict__ Nw) {
#pragma unroll
        for (int nt = 0; nt < 4; ++nt)
#pragma unroll
            for (int rg = 0; rg < 4; ++rg)
                Nw[(quad * 4 + rg) * 68 + nt * 16 + m16] = acc[nt][rg];
    };

    // ---- register-resident routing: 3 iterations, no-max softmax (v13) ----
    auto routing_reg = [&](const float4* Nv, float4 c4, bool relu_last) -> float4 {
        float4 h4 = c4;   // iter-0 htmp = hid
#pragma unroll
        for (int it = 0; it < 3; ++it) {
            float es[4];
#pragma unroll
            for (int t = 0; t < 4; ++t) {
                float d = h4.x * Nv[t].x + h4.y * Nv[t].y +
                          h4.z * Nv[t].z + h4.w * Nv[t].w;
                d += __shfl_xor(d, 1);        // + other half of the octet
                es[t] = __expf(d * SCALE);
            }
            float sm = (es[0] + es[1]) + (es[2] + es[3]);
            sm += __shfl_xor(sm, 16);
            sm += __shfl_xor(sm, 32);
            float inv = 1.0f / sm;
            float a0 = es[0] * inv, a1 = es[1] * inv;
            float a2 = es[2] * inv, a3 = es[3] * inv;
            float4 z;
            z.x = a0 * Nv[0].x; z.y = a0 * Nv[0].y; z.z = a0 * Nv[0].z; z.w = a0 * Nv[0].w;
            z.x = fmaf(a1, Nv[1].x, z.x); z.y = fmaf(a1, Nv[1].y, z.y);
            z.z = fmaf(a1, Nv[1].z, z.z); z.w = fmaf(a1, Nv[1].w, z.w);
            z.x = fmaf(a2, Nv[2].x, z.x); z.y = fmaf(a2, Nv[2].y, z.y);
            z.z = fmaf(a2, Nv[2].z, z.z); z.w = fmaf(a2, Nv[2].w, z.w);
            z.x = fmaf(a3, Nv[3].x, z.x); z.y = fmaf(a3, Nv[3].y, z.y);
            z.z = fmaf(a3, Nv[3].z, z.z); z.w = fmaf(a3, Nv[3].w, z.w);
            z.x += __shfl_xor(z.x, 16); z.y += __shfl_xor(z.y, 16);
            z.z += __shfl_xor(z.z, 16); z.w += __shfl_xor(z.w, 16);
            z.x += __shfl_xor(z.x, 32); z.y += __shfl_xor(z.y, 32);
            z.z += __shfl_xor(z.z, 32); z.w += __shfl_xor(z.w, 32);
            h4.x = c4.x + z.x; h4.y = c4.y + z.y;
            h4.z = c4.z + z.z; h4.w = c4.w + z.w;
            if (relu_last && it == 2) {
                h4.x = fmaxf(h4.x, 0.f); h4.y = fmaxf(h4.y, 0.f);
                h4.z = fmaxf(h4.z, 0.f); h4.w = fmaxf(h4.w, 0.f);
            }
        }
        return h4;
    };

    // rolling gidx loader: slot u -> batch u>>2, q = u&3   (u in 0..7)
    auto gload = [&](int u) {
        return idx2[bidx[u >> 2] * 256 + (wv * 4 + (u & 3)) * 16 + m16];
    };

    // ================= layer-1 pre-encode: hid = e1 @ W1c (2 batches) =========
    load_wfrag(w1c_id);
#pragma unroll
    for (int bb = 0; bb < 2; ++bb) {
        const float* p1 = &tab1[(long)idx1[bidx[bb] * 16 + m16] * 64 + quad * 8];
        float4 e1a = *(const float4*)p1;
        float4 e1b = *(const float4*)(p1 + 4);
        float4 e1c = *(const float4*)(p1 + 32);
        float4 e1d = *(const float4*)(p1 + 36);
        floatx4 hacc[4];
        mfma_compute(e1a, e1b, e1c, e1d, hacc);
        // D: row = quad*4+reg, col = nt*16+m16. Wave w keeps rows w*4..w*4+3
        // (quad==wv lanes) — exactly its own routing slots. fp16 store.
        if (quad == wv) {
#pragma unroll
            for (int nt = 0; nt < 4; ++nt)
#pragma unroll
                for (int rg = 0; rg < 4; ++rg)
                    sC[(bb * 16 + quad * 4 + rg) * SCP + nt * 16 + m16] =
                        (_Float16)hacc[nt][rg];
        }
    }
    __builtin_amdgcn_wave_barrier();

    // ================= layer-1 main: 8 slots (2 batches x 4), pipelined ======
    load_wfrag(w1n_id);
    float4 f0, f1, f2, f3;
    {
        const float* p = &tab0[(long)gload(0) * 64 + quad * 8];
        f0 = *(const float4*)p;        f1 = *(const float4*)(p + 4);
        f2 = *(const float4*)(p + 32); f3 = *(const float4*)(p + 36);
    }
    floatx4 accA[4], accB[4];
    mfma_compute(f0, f1, f2, f3, accA);           // slot 0
    {
        const float* p = &tab0[(long)gload(1) * 64 + quad * 8];
        f0 = *(const float4*)p;        f1 = *(const float4*)(p + 4);
        f2 = *(const float4*)(p + 32); f3 = *(const float4*)(p + 36);
    }
#pragma unroll
    for (int u = 0; u < 8; ++u) {
        const int srow = (u >> 2) * 16 + wv * 4 + (u & 3);
        const floatx4* accCur = (u & 1) ? accB : accA;
        floatx4* accNxt       = (u & 1) ? accA : accB;
        __builtin_amdgcn_wave_barrier();
        store_tile(accCur, sN[wv]);
        __builtin_amdgcn_wave_barrier();
        float4 Nv[4];
#pragma unroll
        for (int t = 0; t < 4; ++t)
            Nv[t] = *(const float4*)&sN[wv][(4 * rr + t) * 68 + 4 * j4];
        __builtin_amdgcn_wave_barrier();
        if (u < 7) {
            mfma_compute(f0, f1, f2, f3, accNxt);  // slot u+1, overlaps routing(u)
            if (u < 6) {   // prefetch slot u+2's A rows (rolling gidx)
                const float* p = &tab0[(long)gload(u + 2) * 64 + quad * 8];
                f0 = *(const float4*)p;        f1 = *(const float4*)(p + 4);
                f2 = *(const float4*)(p + 32); f3 = *(const float4*)(p + 36);
            }
        }
        half4 ch = *(const half4*)&sC[srow * SCP + 4 * j4];  // reg-held hid (fp16)
        float4 c4;
        c4.x = (float)ch[0]; c4.y = (float)ch[1];
        c4.z = (float)ch[2]; c4.w = (float)ch[3];
        float4 h4 = routing_reg(Nv, c4, true);
        if (rr == 0) {   // h1 overwrites dead hid row (fp16)
            half4 hh;
            hh[0] = (_Float16)h4.x; hh[1] = (_Float16)h4.y;
            hh[2] = (_Float16)h4.z; hh[3] = (_Float16)h4.w;
            *(half4*)&sC[srow * SCP + 4 * j4] = hh;
        }
    }

    // ================= layer-0: wave wv (wv<2) -> batch bidx[wv] ==============
    __syncthreads();   // the only block barrier: all h1 rows visible
    if (wv < 2) {
        load_wfrag(w0n_id);
        sE0[wv][lane] = v0;
        floatx4 acc[4];
        {
            // batch wv's h1 rows, already fp16: load A-frags directly
            const _Float16* hp = &sC[(wv * 16 + m16) * SCP];
            half8 A0 = *(const half8*)(hp + quad * 8);
            half8 A1 = *(const half8*)(hp + 32 + quad * 8);
            mfma_compute_h(A0, A1, acc);
        }
        __builtin_amdgcn_wave_barrier();
        store_tile(acc, sN[wv]);
        __builtin_amdgcn_wave_barrier();
        float4 Nv[4];
#pragma unroll
        for (int t = 0; t < 4; ++t)
            Nv[t] = *(const float4*)&sN[wv][(4 * rr + t) * 68 + 4 * j4];
        float4 c4 = *(const float4*)&sE0[wv][4 * j4];
        float4 h4 = routing_reg(Nv, c4, false);   // no relu in layer-0
        if (rr == 0 && b_base + wv < B)
            *(float4*)&out[((long)branch * B + bidx[wv]) * 64 + 4 * j4] = h4;
    }
}

extern "C" void kernel_launch(void* const* d_in, const int* in_sizes, int n_in,
                              void* d_out, int out_size, void* d_ws, size_t ws_size,
                              hipStream_t stream) {
    const float* user_table = (const float*)d_in[0];
    const float* item_table = (const float*)d_in[1];
    const float* W0u = (const float*)d_in[2];
    const float* W0i = (const float*)d_in[3];
    const float* W1u = (const float*)d_in[4];
    const float* W1i = (const float*)d_in[5];
    const int* uidx0 = (const int*)d_in[6];
    const int* uidx1 = (const int*)d_in[7];
    const int* uidx2 = (const int*)d_in[8];
    const int* iidx0 = (const int*)d_in[9];
    const int* iidx1 = (const int*)d_in[10];
    const int* iidx2 = (const int*)d_in[11];
    float* out = (float*)d_out;
    half8* pk = (half8*)d_ws;   // 4 matrices * 8 frags * 64 lanes * 16B = 32 KB

    const int B = in_sizes[6];  // 2048
    hipLaunchKernelGGL(pack_weights, dim3(4), dim3(256), 0, stream,
                       W0u, W0i, W1u, W1i, pk);
    dim3 grid((B + 1) / 2, 2), block(NTH);
    hipLaunchKernelGGL(disenhan_mfma, grid, block, 0, stream,
                       user_table, item_table, (const half8*)pk,
                       uidx0, uidx1, uidx2, iidx0, iidx1, iidx2, out, B);
}

// Round 3
// 154.838 us; speedup vs baseline: 1.4842x; 1.0237x over previous
//
#include <hip/hip_runtime.h>
#include <hip/hip_bf16.h>
#include <hip/hip_fp16.h>

// DisenHAN fused, single-pass FP16 MFMA edition, v18 (gfx950).
// v18 = v17 with ALL routing shuffles moved off the DS pipe:
//   xor1  -> DPP quad_perm(1,0,3,2) mov + add      (VALU)
//   xor16 -> v_permlane16_swap_b32 pair-sum        (VALU, gfx950)
//   xor32 -> v_permlane32_swap_b32 pair-sum        (VALU, gfx950)
// Theory: v15/v17 both sit at 73us, Occ ~35%, VALU ~48% regardless of
// LDS/grid (residency levers dead). Block lifetime ~12.5us vs ~1.3us of
// VALU issue -> latency-bound on the routing dep chain: 14 serial-ish
// DS shuffles per iter x 27 iters = 378 DS round-trips/thread (~60-120cy
// each). permlane swap with D0=D1=x yields D0+D1 = pair-sum broadcast in
// 2 VALU ops; every shuffle here IS a pair-sum. DS shuffles -> 0.
// Summation grouping unchanged -> bitwise-identical math, absmax same.
// v17 recap: 2 batches/block (grid (B/2,2)), 8 slots, fp16 sC (pitch 72),
// LDS 22528B, launch_bounds(256,4) (NEVER tighter: v16 spilled at (256,7),
// VGPR 60->36, WRITE 1->91MB, 137us). 4-block pack kernel -> fp16 B-frags
// in d_ws; single-pass mfma_f32_16x16x32_f16; no-max softmax; pipelined
// slot loop w/ double-buffered acc; register-resident routing; h1
// overwrites dead hid row in sC. T=1: beta==1, wp==1 forever.

#define NTH 256

typedef __attribute__((ext_vector_type(8))) _Float16 half8;  // 8 fp16 (4 VGPRs)
typedef __attribute__((ext_vector_type(4))) _Float16 half4;
typedef __attribute__((ext_vector_type(4))) float floatx4;
typedef unsigned __attribute__((ext_vector_type(2))) uint2v;

__device__ __forceinline__ half8 pack8_f16(float4 a, float4 b) {
    half8 r;
    r[0] = (_Float16)a.x; r[1] = (_Float16)a.y;
    r[2] = (_Float16)a.z; r[3] = (_Float16)a.w;
    r[4] = (_Float16)b.x; r[5] = (_Float16)b.y;
    r[6] = (_Float16)b.z; r[7] = (_Float16)b.w;
    return r;
}

// ---- VALU pair-sum helpers (no DS pipe) ----
// sum with lane^1 partner: DPP quad_perm [1,0,3,2]
__device__ __forceinline__ float sum_xor1(float x) {
    int y = __builtin_amdgcn_mov_dpp(__float_as_int(x), 0xB1, 0xF, 0xF, true);
    return x + __int_as_float(y);
}
// sum with lane^16 partner: permlane16_swap(x,x) -> D0+D1 = pair-sum
__device__ __forceinline__ float sum_xor16(float x) {
#if __has_builtin(__builtin_amdgcn_permlane16_swap)
    uint2v r = __builtin_amdgcn_permlane16_swap(__float_as_uint(x), __float_as_uint(x),
                                                false, false);
    return __uint_as_float(r[0]) + __uint_as_float(r[1]);
#else
    return x + __shfl_xor(x, 16);
#endif
}
// sum with lane^32 partner: permlane32_swap(x,x) -> D0+D1 = pair-sum
__device__ __forceinline__ float sum_xor32(float x) {
#if __has_builtin(__builtin_amdgcn_permlane32_swap)
    uint2v r = __builtin_amdgcn_permlane32_swap(__float_as_uint(x), __float_as_uint(x),
                                                false, false);
    return __uint_as_float(r[0]) + __uint_as_float(r[1]);
#else
    return x + __shfl_xor(x, 32);
#endif
}

// ---- setup: pack 4 weight matrices into fp16 B-fragment order ----
// layout: frag[ (w*4+nt)*2+ks ][ lane ] = 8 fp16 (16B), coalesced.
__global__ void pack_weights(const float* __restrict__ W0u, const float* __restrict__ W0i,
                             const float* __restrict__ W1u, const float* __restrict__ W1i,
                             half8* __restrict__ pk) {
    const float* Ws[4] = {W0u, W0i, W1u, W1i};
    const int w = blockIdx.x;
    const int wv = threadIdx.x >> 6, lane = threadIdx.x & 63;
    const int quad = lane >> 4, m16 = lane & 15;
    const int nt = wv;
    const float* W = Ws[w];
#pragma unroll
    for (int ks = 0; ks < 2; ++ks) {
        half8 f;
#pragma unroll
        for (int j = 0; j < 8; ++j)
            f[j] = (_Float16)W[(ks * 32 + quad * 8 + j) * 64 + nt * 16 + m16];
        pk[(long)(((w * 4 + nt) * 2 + ks)) * 64 + lane] = f;
    }
}

__global__ __launch_bounds__(256, 4)
void disenhan_mfma(const float* __restrict__ user_table,
                   const float* __restrict__ item_table,
                   const half8* __restrict__ pk,
                   const int* __restrict__ uidx0, const int* __restrict__ uidx1,
                   const int* __restrict__ uidx2,
                   const int* __restrict__ iidx0, const int* __restrict__ iidx1,
                   const int* __restrict__ iidx2,
                   float* __restrict__ out, int B)
{
    constexpr float SCALE = 0.35355339059327373f;  // 1/sqrt(8)
    constexpr int SCP = 72;   // sC pitch in halfs (144B: 16B-aligned rows)
    const int branch = blockIdx.y;
    const int tid = threadIdx.x;
    const int wv = tid >> 6, lane = tid & 63;
    const int quad = lane >> 4;   // MFMA k-block selector
    const int m16  = lane & 15;   // MFMA row (A) / col (B,D) selector
    const int rr   = lane >> 4;   // routing: row group (rows 4rr..4rr+3)
    const int j4   = lane & 15;   // routing: col group (cols 4j4..4j4+3)

    const int b_base = blockIdx.x * 2;
    int bidx[2];
#pragma unroll
    for (int bb = 0; bb < 2; ++bb) {
        int bc = b_base + bb;
        bidx[bb] = (bc < B) ? bc : (B - 1);   // tail guard: duplicate work, benign
    }

    // matrix ids in pk: 0=W0u 1=W0i 2=W1u 3=W1i
    const float *tab0, *tab1;
    const int *idx0, *idx1, *idx2;
    int w1c_id, w1n_id, w0n_id;
    if (branch == 0) { tab0 = user_table; tab1 = item_table;
                       idx0 = uidx0; idx1 = uidx1; idx2 = uidx2;
                       w1c_id = 3; w1n_id = 2; w0n_id = 1; }
    else             { tab0 = item_table; tab1 = user_table;
                       idx0 = iidx0; idx1 = iidx1; idx2 = iidx2;
                       w1c_id = 2; w1n_id = 3; w0n_id = 0; }

    __shared__ float    sN[4][16 * 68];  // per-wave nh tile (fp32, pitch 68)
    __shared__ _Float16 sC[32 * SCP];    // hid rows (2 batches x 16, fp16); h1 overwrites
    __shared__ float    sE0[2][64];      // layer-0 centers (e0), one per batch

    // e0 prefetch: wave wv (wv<2) serves batch bidx[wv] in the tail
    float v0 = 0.f;
    if (wv < 2) v0 = tab0[(long)idx0[bidx[wv]] * 64 + lane];

    // ---- B-fragment loader: 8 coalesced 16B loads from the packed buffer ----
    half8 wf[4][2];
    auto load_wfrag = [&](int w) {
#pragma unroll
        for (int nt = 0; nt < 4; ++nt)
#pragma unroll
            for (int ks = 0; ks < 2; ++ks)
                wf[nt][ks] = pk[(long)(((w * 4 + nt) * 2 + ks)) * 64 + lane];
    };

    // ---- MFMA tile compute (no LDS side effects) ----
    auto mfma_compute_h = [&](half8 A0, half8 A1, floatx4* acc) {
#pragma unroll
        for (int nt = 0; nt < 4; ++nt) {
            acc[nt] = (floatx4){0.f, 0.f, 0.f, 0.f};
            acc[nt] = __builtin_amdgcn_mfma_f32_16x16x32_f16(A0, wf[nt][0], acc[nt], 0, 0, 0);
            acc[nt] = __builtin_amdgcn_mfma_f32_16x16x32_f16(A1, wf[nt][1], acc[nt], 0, 0, 0);
        }
    };
    auto mfma_compute = [&](float4 f0, float4 f1, float4 f2, float4 f3,
                            floatx4* acc) {
        mfma_compute_h(pack8_f16(f0, f1), pack8_f16(f2, f3), acc);
    };
    auto store_tile = [&](const floatx4* acc, float* __restrict__ Nw) {
#pragma unroll
        for (int nt = 0; nt < 4; ++nt)
#pragma unroll
            for (int rg = 0; rg < 4; ++rg)
                Nw[(quad * 4 + rg) * 68 + nt * 16 + m16] = acc[nt][rg];
    };

    // ---- register-resident routing: 3 iterations, no-max softmax ----
    // All cross-lane sums on the VALU pipe (DPP / permlane swap), 0 DS ops.
    auto routing_reg = [&](const float4* Nv, float4 c4, bool relu_last) -> float4 {
        float4 h4 = c4;   // iter-0 htmp = hid
#pragma unroll
        for (int it = 0; it < 3; ++it) {
            float es[4];
#pragma unroll
            for (int t = 0; t < 4; ++t) {
                float d = h4.x * Nv[t].x + h4.y * Nv[t].y +
                          h4.z * Nv[t].z + h4.w * Nv[t].w;
                d = sum_xor1(d);              // + other half of the octet
                es[t] = __expf(d * SCALE);
            }
            float sm = (es[0] + es[1]) + (es[2] + es[3]);
            sm = sum_xor32(sum_xor16(sm));
            float inv = 1.0f / sm;
            float a0 = es[0] * inv, a1 = es[1] * inv;
            float a2 = es[2] * inv, a3 = es[3] * inv;
            float4 z;
            z.x = a0 * Nv[0].x; z.y = a0 * Nv[0].y; z.z = a0 * Nv[0].z; z.w = a0 * Nv[0].w;
            z.x = fmaf(a1, Nv[1].x, z.x); z.y = fmaf(a1, Nv[1].y, z.y);
            z.z = fmaf(a1, Nv[1].z, z.z); z.w = fmaf(a1, Nv[1].w, z.w);
            z.x = fmaf(a2, Nv[2].x, z.x); z.y = fmaf(a2, Nv[2].y, z.y);
            z.z = fmaf(a2, Nv[2].z, z.z); z.w = fmaf(a2, Nv[2].w, z.w);
            z.x = fmaf(a3, Nv[3].x, z.x); z.y = fmaf(a3, Nv[3].y, z.y);
            z.z = fmaf(a3, Nv[3].z, z.z); z.w = fmaf(a3, Nv[3].w, z.w);
            z.x = sum_xor32(sum_xor16(z.x));
            z.y = sum_xor32(sum_xor16(z.y));
            z.z = sum_xor32(sum_xor16(z.z));
            z.w = sum_xor32(sum_xor16(z.w));
            h4.x = c4.x + z.x; h4.y = c4.y + z.y;
            h4.z = c4.z + z.z; h4.w = c4.w + z.w;
            if (relu_last && it == 2) {
                h4.x = fmaxf(h4.x, 0.f); h4.y = fmaxf(h4.y, 0.f);
                h4.z = fmaxf(h4.z, 0.f); h4.w = fmaxf(h4.w, 0.f);
            }
        }
        return h4;
    };

    // rolling gidx loader: slot u -> batch u>>2, q = u&3   (u in 0..7)
    auto gload = [&](int u) {
        return idx2[bidx[u >> 2] * 256 + (wv * 4 + (u & 3)) * 16 + m16];
    };

    // ================= layer-1 pre-encode: hid = e1 @ W1c (2 batches) =========
    load_wfrag(w1c_id);
#pragma unroll
    for (int bb = 0; bb < 2; ++bb) {
        const float* p1 = &tab1[(long)idx1[bidx[bb] * 16 + m16] * 64 + quad * 8];
        float4 e1a = *(const float4*)p1;
        float4 e1b = *(const float4*)(p1 + 4);
        float4 e1c = *(const float4*)(p1 + 32);
        float4 e1d = *(const float4*)(p1 + 36);
        floatx4 hacc[4];
        mfma_compute(e1a, e1b, e1c, e1d, hacc);
        // D: row = quad*4+reg, col = nt*16+m16. Wave w keeps rows w*4..w*4+3
        // (quad==wv lanes) — exactly its own routing slots. fp16 store.
        if (quad == wv) {
#pragma unroll
            for (int nt = 0; nt < 4; ++nt)
#pragma unroll
                for (int rg = 0; rg < 4; ++rg)
                    sC[(bb * 16 + quad * 4 + rg) * SCP + nt * 16 + m16] =
                        (_Float16)hacc[nt][rg];
        }
    }
    __builtin_amdgcn_wave_barrier();

    // ================= layer-1 main: 8 slots (2 batches x 4), pipelined ======
    load_wfrag(w1n_id);
    float4 f0, f1, f2, f3;
    {
        const float* p = &tab0[(long)gload(0) * 64 + quad * 8];
        f0 = *(const float4*)p;        f1 = *(const float4*)(p + 4);
        f2 = *(const float4*)(p + 32); f3 = *(const float4*)(p + 36);
    }
    floatx4 accA[4], accB[4];
    mfma_compute(f0, f1, f2, f3, accA);           // slot 0
    {
        const float* p = &tab0[(long)gload(1) * 64 + quad * 8];
        f0 = *(const float4*)p;        f1 = *(const float4*)(p + 4);
        f2 = *(const float4*)(p + 32); f3 = *(const float4*)(p + 36);
    }
#pragma unroll
    for (int u = 0; u < 8; ++u) {
        const int srow = (u >> 2) * 16 + wv * 4 + (u & 3);
        const floatx4* accCur = (u & 1) ? accB : accA;
        floatx4* accNxt       = (u & 1) ? accA : accB;
        __builtin_amdgcn_wave_barrier();
        store_tile(accCur, sN[wv]);
        __builtin_amdgcn_wave_barrier();
        float4 Nv[4];
#pragma unroll
        for (int t = 0; t < 4; ++t)
            Nv[t] = *(const float4*)&sN[wv][(4 * rr + t) * 68 + 4 * j4];
        __builtin_amdgcn_wave_barrier();
        if (u < 7) {
            mfma_compute(f0, f1, f2, f3, accNxt);  // slot u+1, overlaps routing(u)
            if (u < 6) {   // prefetch slot u+2's A rows (rolling gidx)
                const float* p = &tab0[(long)gload(u + 2) * 64 + quad * 8];
                f0 = *(const float4*)p;        f1 = *(const float4*)(p + 4);
                f2 = *(const float4*)(p + 32); f3 = *(const float4*)(p + 36);
            }
        }
        half4 ch = *(const half4*)&sC[srow * SCP + 4 * j4];  // reg-held hid (fp16)
        float4 c4;
        c4.x = (float)ch[0]; c4.y = (float)ch[1];
        c4.z = (float)ch[2]; c4.w = (float)ch[3];
        float4 h4 = routing_reg(Nv, c4, true);
        if (rr == 0) {   // h1 overwrites dead hid row (fp16)
            half4 hh;
            hh[0] = (_Float16)h4.x; hh[1] = (_Float16)h4.y;
            hh[2] = (_Float16)h4.z; hh[3] = (_Float16)h4.w;
            *(half4*)&sC[srow * SCP + 4 * j4] = hh;
        }
    }

    // ================= layer-0: wave wv (wv<2) -> batch bidx[wv] ==============
    __syncthreads();   // the only block barrier: all h1 rows visible
    if (wv < 2) {
        load_wfrag(w0n_id);
        sE0[wv][lane] = v0;
        floatx4 acc[4];
        {
            // batch wv's h1 rows, already fp16: load A-frags directly
            const _Float16* hp = &sC[(wv * 16 + m16) * SCP];
            half8 A0 = *(const half8*)(hp + quad * 8);
            half8 A1 = *(const half8*)(hp + 32 + quad * 8);
            mfma_compute_h(A0, A1, acc);
        }
        __builtin_amdgcn_wave_barrier();
        store_tile(acc, sN[wv]);
        __builtin_amdgcn_wave_barrier();
        float4 Nv[4];
#pragma unroll
        for (int t = 0; t < 4; ++t)
            Nv[t] = *(const float4*)&sN[wv][(4 * rr + t) * 68 + 4 * j4];
        float4 c4 = *(const float4*)&sE0[wv][4 * j4];
        float4 h4 = routing_reg(Nv, c4, false);   // no relu in layer-0
        if (rr == 0 && b_base + wv < B)
            *(float4*)&out[((long)branch * B + bidx[wv]) * 64 + 4 * j4] = h4;
    }
}

extern "C" void kernel_launch(void* const* d_in, const int* in_sizes, int n_in,
                              void* d_out, int out_size, void* d_ws, size_t ws_size,
                              hipStream_t stream) {
    const float* user_table = (const float*)d_in[0];
    const float* item_table = (const float*)d_in[1];
    const float* W0u = (const float*)d_in[2];
    const float* W0i = (const float*)d_in[3];
    const float* W1u = (const float*)d_in[4];
    const float* W1i = (const float*)d_in[5];
    const int* uidx0 = (const int*)d_in[6];
    const int* uidx1 = (const int*)d_in[7];
    const int* uidx2 = (const int*)d_in[8];
    const int* iidx0 = (const int*)d_in[9];
    const int* iidx1 = (const int*)d_in[10];
    const int* iidx2 = (const int*)d_in[11];
    float* out = (float*)d_out;
    half8* pk = (half8*)d_ws;   // 4 matrices * 8 frags * 64 lanes * 16B = 32 KB

    const int B = in_sizes[6];  // 2048
    hipLaunchKernelGGL(pack_weights, dim3(4), dim3(256), 0, stream,
                       W0u, W0i, W1u, W1i, pk);
    dim3 grid((B + 1) / 2, 2), block(NTH);
    hipLaunchKernelGGL(disenhan_mfma, grid, block, 0, stream,
                       user_table, item_table, (const half8*)pk,
                       uidx0, uidx1, uidx2, iidx0, iidx1, iidx2, out, B);
}